// Round 1
// baseline (174.782 us; speedup 1.0000x reference)
//
#include <hip/hip_runtime.h>
#include <hip/hip_bf16.h>

typedef __attribute__((ext_vector_type(8))) short bf16x8;
typedef __attribute__((ext_vector_type(4))) float f32x4;

#define NROWS 8192
#define F_DIM 128
#define Q_DIM 64
#define KPAD  224   // 193 padded to 7*32
#define H_DIM 256

// ---- norm + bf16 normalize + zero cnt -------------------------------------
__global__ __launch_bounds__(256) void norm_kernel(const float* __restrict__ x,
                                                   __hip_bfloat16* __restrict__ xn,
                                                   int* __restrict__ cnt) {
  int tid = threadIdx.x;
  int lane = tid & 63;
  int row = blockIdx.x * 4 + (tid >> 6);
  if (blockIdx.x < 32) cnt[blockIdx.x * 256 + tid] = 0;
  const float2 v = *(const float2*)(x + (size_t)row * F_DIM + lane * 2);
  float s = v.x * v.x + v.y * v.y;
#pragma unroll
  for (int off = 32; off; off >>= 1) s += __shfl_xor(s, off);
  float inv = 1.0f / (sqrtf(s) + 1e-12f);
  __hip_bfloat162 p;
  p.x = __float2bfloat16(v.x * inv);
  p.y = __float2bfloat16(v.y * inv);
  *(__hip_bfloat162*)(xn + (size_t)row * F_DIM + lane * 2) = p;
}

// ---- Gram + square + threshold + row-count --------------------------------
// grid (64,64); block 256 = 4 waves; each wave one 64x64 quadrant of a
// 128x128 output tile. MFMA 16x16x32 bf16, K=128.
__global__ __launch_bounds__(256) void gram_kernel(const __hip_bfloat16* __restrict__ xnp,
                                                   int* __restrict__ cnt) {
  const short* xn = (const short*)xnp;
  int tid = threadIdx.x;
  int lane = tid & 63;
  int wave = tid >> 6;
  int i_base = blockIdx.x * 128 + (wave >> 1) * 64;
  int j_base = blockIdx.y * 128 + (wave & 1) * 64;
  int lr = lane & 15;
  int quad = lane >> 4;

  f32x4 acc[4][4];
#pragma unroll
  for (int i = 0; i < 4; i++)
#pragma unroll
    for (int j = 0; j < 4; j++) acc[i][j] = (f32x4){0.f, 0.f, 0.f, 0.f};

#pragma unroll
  for (int kk = 0; kk < 4; kk++) {
    int ko = kk * 32 + quad * 8;
    bf16x8 a[4], b[4];
#pragma unroll
    for (int t = 0; t < 4; t++)
      a[t] = *(const bf16x8*)(xn + (size_t)(i_base + t * 16 + lr) * F_DIM + ko);
#pragma unroll
    for (int t = 0; t < 4; t++)
      b[t] = *(const bf16x8*)(xn + (size_t)(j_base + t * 16 + lr) * F_DIM + ko);
#pragma unroll
    for (int tr = 0; tr < 4; tr++)
#pragma unroll
      for (int tc = 0; tc < 4; tc++)
        acc[tr][tc] = __builtin_amdgcn_mfma_f32_16x16x32_bf16(a[tr], b[tc], acc[tr][tc], 0, 0, 0);
  }

  // count fid >= 0.95 per output row (exclude diagonal)
#pragma unroll
  for (int tr = 0; tr < 4; tr++) {
    int row0 = i_base + tr * 16 + quad * 4;
#pragma unroll
    for (int r = 0; r < 4; r++) {
      int c = 0;
#pragma unroll
      for (int tc = 0; tc < 4; tc++) {
        float v = acc[tr][tc][r];
        int col = j_base + tc * 16 + lr;
        c += (v * v >= 0.95f && (row0 + r) != col) ? 1 : 0;
      }
      c += __shfl_xor(c, 1);
      c += __shfl_xor(c, 2);
      c += __shfl_xor(c, 4);
      c += __shfl_xor(c, 8);
      if (lr == 0 && c) atomicAdd(&cnt[row0 + r], c);
    }
  }
}

// ---- weight transpose (+ zero-pad W1T rows 193..223) ----------------------
__global__ void tw_kernel(const float* __restrict__ W1, const float* __restrict__ W2,
                          float* __restrict__ W1T, float* __restrict__ W2T) {
  int d = blockIdx.x;
  int n = threadIdx.x;
  if (d < KPAD) {
    W1T[d * 256 + n] = (d < 193) ? W1[n * 193 + d] : 0.0f;
  } else {
    int dd = d - KPAD;
    W2T[dd * 256 + n] = W2[n * 256 + dd];
  }
}

// ---- build feats [8192][224] = [x | q | gf | 0-pad] -----------------------
__global__ void feats_kernel(const float* __restrict__ x, const float* __restrict__ q,
                             const int* __restrict__ cnt, float* __restrict__ feats) {
  int r = blockIdx.x, t = threadIdx.x;
  if (t >= KPAD) return;
  float val;
  if (t < 128)      val = x[(size_t)r * 128 + t];
  else if (t < 192) val = q[(size_t)r * 64 + (t - 128)];
  else if (t == 192) val = (float)cnt[r] * (1.0f / 8192.0f);
  else val = 0.0f;
  feats[(size_t)r * KPAD + t] = val;
}

// ---- fp32 GEMM + bias + relu: C[M][256] = relu(A[M][K] @ WT[K][256] + b) --
// block 256, tile 64x64, thread tile 4x4
template <int K>
__global__ __launch_bounds__(256) void gemm_relu(const float* __restrict__ A,
                                                 const float* __restrict__ WT,
                                                 const float* __restrict__ bias,
                                                 float* __restrict__ C) {
  __shared__ float As[64][36];
  __shared__ float Ws[32][64];
  int tid = threadIdx.x;
  int bi = blockIdx.x, bj = blockIdx.y;
  int tx = tid & 15, ty = tid >> 4;
  int ar = tid >> 2, ak = (tid & 3) * 8;
  int wr = tid >> 3, wc = (tid & 7) * 8;
  f32x4 acc[4];
#pragma unroll
  for (int i = 0; i < 4; i++) acc[i] = (f32x4){0.f, 0.f, 0.f, 0.f};

  for (int k0 = 0; k0 < K; k0 += 32) {
    const float* ap = A + (size_t)(bi * 64 + ar) * K + k0 + ak;
    float4 a0 = *(const float4*)(ap);
    float4 a1 = *(const float4*)(ap + 4);
    const float* wp = WT + (size_t)(k0 + wr) * 256 + bj * 64 + wc;
    float4 w0 = *(const float4*)(wp);
    float4 w1 = *(const float4*)(wp + 4);
    __syncthreads();
    *(float4*)&As[ar][ak] = a0;
    *(float4*)&As[ar][ak + 4] = a1;
    *(float4*)&Ws[wr][wc] = w0;
    *(float4*)&Ws[wr][wc + 4] = w1;
    __syncthreads();
#pragma unroll
    for (int kk = 0; kk < 32; kk += 4) {
      f32x4 av[4], wv[4];
#pragma unroll
      for (int i = 0; i < 4; i++) av[i] = *(const f32x4*)&As[ty * 4 + i][kk];
#pragma unroll
      for (int s = 0; s < 4; s++) wv[s] = *(const f32x4*)&Ws[kk + s][tx * 4];
#pragma unroll
      for (int i = 0; i < 4; i++) {
        acc[i] += av[i].x * wv[0];
        acc[i] += av[i].y * wv[1];
        acc[i] += av[i].z * wv[2];
        acc[i] += av[i].w * wv[3];
      }
    }
  }

  int colbase = bj * 64 + tx * 4;
  f32x4 bv = *(const f32x4*)(bias + colbase);
#pragma unroll
  for (int i = 0; i < 4; i++) {
    f32x4 o = acc[i] + bv;
    o.x = fmaxf(o.x, 0.f);
    o.y = fmaxf(o.y, 0.f);
    o.z = fmaxf(o.z, 0.f);
    o.w = fmaxf(o.w, 0.f);
    *(f32x4*)(C + (size_t)(bi * 64 + ty * 4 + i) * 256 + colbase) = o;
  }
}

// ---- final layer: out[r] = dot(h2[r], W3) + b3 ----------------------------
__global__ __launch_bounds__(256) void layer3_kernel(const float* __restrict__ h2,
                                                     const float* __restrict__ W3,
                                                     const float* __restrict__ b3,
                                                     float* __restrict__ out) {
  int tid = threadIdx.x;
  int lane = tid & 63;
  int row = blockIdx.x * 4 + (tid >> 6);
  f32x4 h = *(const f32x4*)(h2 + (size_t)row * 256 + lane * 4);
  f32x4 w = *(const f32x4*)(W3 + lane * 4);
  float s = h.x * w.x + h.y * w.y + h.z * w.z + h.w * w.w;
#pragma unroll
  for (int off = 32; off; off >>= 1) s += __shfl_xor(s, off);
  if (lane == 0) out[row] = s + b3[0];
}

extern "C" void kernel_launch(void* const* d_in, const int* in_sizes, int n_in,
                              void* d_out, int out_size, void* d_ws, size_t ws_size,
                              hipStream_t stream) {
  const float* x  = (const float*)d_in[0];
  const float* q  = (const float*)d_in[1];
  const float* W1 = (const float*)d_in[2];
  const float* b1 = (const float*)d_in[3];
  const float* W2 = (const float*)d_in[4];
  const float* b2 = (const float*)d_in[5];
  const float* W3 = (const float*)d_in[6];
  const float* b3 = (const float*)d_in[7];
  float* out = (float*)d_out;

  char* ws = (char*)d_ws;
  __hip_bfloat16* xn = (__hip_bfloat16*)(ws);        // 8192*128*2 = 2 MB
  int*   cnt   = (int*)(ws + 0x200000);              // 32 KB
  float* W1T   = (float*)(ws + 0x210000);            // 224*256*4 = 224 KB
  float* W2T   = (float*)(ws + 0x250000);            // 256*256*4 = 256 KB
  float* feats = (float*)(ws + 0x290000);            // 8192*224*4 = 7 MB
  float* h1    = (float*)(ws + 0x990000);            // 8192*256*4 = 8 MB
  float* h2    = (float*)(ws + 0x1190000);           // 8 MB  (end ~25.6 MB)

  norm_kernel<<<dim3(2048), dim3(256), 0, stream>>>(x, xn, cnt);
  tw_kernel<<<dim3(KPAD + 256), dim3(256), 0, stream>>>(W1, W2, W1T, W2T);
  gram_kernel<<<dim3(64, 64), dim3(256), 0, stream>>>(xn, cnt);
  feats_kernel<<<dim3(8192), dim3(256), 0, stream>>>(x, q, cnt, feats);
  gemm_relu<KPAD><<<dim3(128, 4), dim3(256), 0, stream>>>(feats, W1T, b1, h1);
  gemm_relu<256><<<dim3(128, 4), dim3(256), 0, stream>>>(h1, W2T, b2, h2);
  layer3_kernel<<<dim3(2048), dim3(256), 0, stream>>>(h2, W3, b3, out);
}

// Round 2
// 126.520 us; speedup vs baseline: 1.3815x; 1.3815x over previous
//
#include <hip/hip_runtime.h>
#include <hip/hip_bf16.h>

typedef __attribute__((ext_vector_type(8))) short bf16x8;
typedef __attribute__((ext_vector_type(4))) float f32x4;

#define NROWS 8192
#define F_DIM 128
#define Q_DIM 64
#define KPAD  224   // 193 padded to 7*32
#define H_DIM 256

// ---- norm + bf16 normalize + zero cnt -------------------------------------
__global__ __launch_bounds__(256) void norm_kernel(const float* __restrict__ x,
                                                   __hip_bfloat16* __restrict__ xn,
                                                   int* __restrict__ cnt) {
  int tid = threadIdx.x;
  int lane = tid & 63;
  int row = blockIdx.x * 4 + (tid >> 6);
  if (blockIdx.x < 32) cnt[blockIdx.x * 256 + tid] = 0;
  const float2 v = *(const float2*)(x + (size_t)row * F_DIM + lane * 2);
  float s = v.x * v.x + v.y * v.y;
#pragma unroll
  for (int off = 32; off; off >>= 1) s += __shfl_xor(s, off);
  float inv = 1.0f / (sqrtf(s) + 1e-12f);
  __hip_bfloat162 p;
  p.x = __float2bfloat16(v.x * inv);
  p.y = __float2bfloat16(v.y * inv);
  *(__hip_bfloat162*)(xn + (size_t)row * F_DIM + lane * 2) = p;
}

// ---- Gram + square + threshold + row-count --------------------------------
// Upper-triangle 128x128 tiles only (2080 blocks). LDS-staged with XOR
// swizzle (2-way max bank aliasing = free). Ballot fast-path epilogue.
__global__ __launch_bounds__(256) void gram_kernel(const __hip_bfloat16* __restrict__ xnp,
                                                   int* __restrict__ cnt) {
  __shared__ char smem[65536];  // 32KB A rows + 32KB B rows, swizzled
  const short* xn = (const short*)xnp;
  int tid = threadIdx.x;
  int lane = tid & 63;
  int wave = tid >> 6;
  int lr = lane & 15;
  int quad = lane >> 4;

  // decode upper-triangle (bi, bj), bj >= bi, from linear block id
  int t = blockIdx.x;
  int bi = (int)((129.0f - sqrtf(129.0f * 129.0f - 8.0f * (float)t)) * 0.5f);
  while ((bi + 1) * (129 - (bi + 1)) / 2 <= t) bi++;
  while (bi * (129 - bi) / 2 > t) bi--;
  int bj = bi + (t - bi * (129 - bi) / 2);
  int i0 = bi * 128, j0 = bj * 128;

  // ---- cooperative staging: 64KB, coalesced global, swizzled LDS ----
#pragma unroll
  for (int it = 0; it < 16; ++it) {
    int half = it >> 3;                 // 0 = A rows, 1 = B rows
    int row = (it & 7) * 16 + (tid >> 4);
    int chunk = tid & 15;               // 16B chunk within 256B row
    int grow = (half ? j0 : i0) + row;
    bf16x8 v = *(const bf16x8*)(xn + (size_t)grow * F_DIM + chunk * 8);
    *(bf16x8*)(smem + half * 32768 + row * 256 + ((chunk ^ (row & 15)) << 4)) = v;
  }
  __syncthreads();

  int wi = (wave >> 1) * 64, wj = (wave & 1) * 64;

  f32x4 acc[4][4];
#pragma unroll
  for (int i = 0; i < 4; i++)
#pragma unroll
    for (int j = 0; j < 4; j++) acc[i][j] = (f32x4){0.f, 0.f, 0.f, 0.f};

#pragma unroll
  for (int kk = 0; kk < 4; kk++) {
    int c = kk * 4 + quad;
    bf16x8 a[4], b[4];
#pragma unroll
    for (int tt = 0; tt < 4; tt++) {
      int row = wi + tt * 16 + lr;
      a[tt] = *(const bf16x8*)(smem + row * 256 + ((c ^ lr) << 4));
    }
#pragma unroll
    for (int tt = 0; tt < 4; tt++) {
      int row = wj + tt * 16 + lr;
      b[tt] = *(const bf16x8*)(smem + 32768 + row * 256 + ((c ^ lr) << 4));
    }
#pragma unroll
    for (int tr = 0; tr < 4; tr++)
#pragma unroll
      for (int tc = 0; tc < 4; tc++)
        acc[tr][tc] = __builtin_amdgcn_mfma_f32_16x16x32_bf16(a[tr], b[tc], acc[tr][tc], 0, 0, 0);
  }

  int i_base = i0 + wi, j_base = j0 + wj;
  bool diag_wave = (i_base == j_base);
  bool offdiag_block = (bi != bj);

  // fast path: max|fid^0.5| over this wave's 64 accs (diag entries zeroed)
  float mx = 0.f;
#pragma unroll
  for (int tr = 0; tr < 4; tr++)
#pragma unroll
    for (int tc = 0; tc < 4; tc++)
#pragma unroll
      for (int r = 0; r < 4; r++) {
        float v = acc[tr][tc][r];
        if (diag_wave && tr == tc && lr == quad * 4 + r) v = 0.f;
        mx = fmaxf(mx, fabsf(v));
      }
  if (__any(mx >= 0.9746f)) {
    // slow path (essentially never taken): exact per-entry counting
    for (int tr = 0; tr < 4; tr++)
      for (int tc = 0; tc < 4; tc++)
        for (int r = 0; r < 4; r++) {
          float v = acc[tr][tc][r];
          int row = i_base + tr * 16 + quad * 4 + r;
          int col = j_base + tc * 16 + lr;
          if (v * v >= 0.95f && row != col) {
            atomicAdd(&cnt[row], 1);
            if (offdiag_block) atomicAdd(&cnt[col], 1);
          }
        }
  }
}

// ---- weight transpose (+ zero-pad W1T rows 193..223) ----------------------
__global__ void tw_kernel(const float* __restrict__ W1, const float* __restrict__ W2,
                          float* __restrict__ W1T, float* __restrict__ W2T) {
  int d = blockIdx.x;
  int n = threadIdx.x;
  if (d < KPAD) {
    W1T[d * 256 + n] = (d < 193) ? W1[n * 193 + d] : 0.0f;
  } else {
    int dd = d - KPAD;
    W2T[dd * 256 + n] = W2[n * 256 + dd];
  }
}

// ---- build feats [8192][224] = [x | q | gf | 0-pad], one row per wave -----
__global__ __launch_bounds__(256) void feats_kernel(const float* __restrict__ x, const float* __restrict__ q,
                                                    const int* __restrict__ cnt, float* __restrict__ feats) {
  int tid = threadIdx.x;
  int lane = tid & 63;
  int row = blockIdx.x * 4 + (tid >> 6);
  float4* dst = (float4*)(feats + (size_t)row * KPAD);
  if (lane < 32) {
    dst[lane] = ((const float4*)(x + (size_t)row * 128))[lane];
  } else if (lane < 48) {
    dst[lane] = ((const float4*)(q + (size_t)row * 64))[lane - 32];
  } else if (lane < 56) {
    float4 v = {0.f, 0.f, 0.f, 0.f};
    if (lane == 48) v.x = (float)cnt[row] * (1.0f / 8192.0f);
    dst[lane] = v;
  }
}

// ---- fp32 GEMM + bias + relu: C[M][256] = relu(A[M][K] @ WT[K][256] + b) --
template <int K>
__global__ __launch_bounds__(256) void gemm_relu(const float* __restrict__ A,
                                                 const float* __restrict__ WT,
                                                 const float* __restrict__ bias,
                                                 float* __restrict__ C) {
  __shared__ float As[64][36];
  __shared__ float Ws[32][64];
  int tid = threadIdx.x;
  int bi = blockIdx.x, bj = blockIdx.y;
  int tx = tid & 15, ty = tid >> 4;
  int ar = tid >> 2, ak = (tid & 3) * 8;
  int wr = tid >> 3, wc = (tid & 7) * 8;
  f32x4 acc[4];
#pragma unroll
  for (int i = 0; i < 4; i++) acc[i] = (f32x4){0.f, 0.f, 0.f, 0.f};

  for (int k0 = 0; k0 < K; k0 += 32) {
    const float* ap = A + (size_t)(bi * 64 + ar) * K + k0 + ak;
    float4 a0 = *(const float4*)(ap);
    float4 a1 = *(const float4*)(ap + 4);
    const float* wp = WT + (size_t)(k0 + wr) * 256 + bj * 64 + wc;
    float4 w0 = *(const float4*)(wp);
    float4 w1 = *(const float4*)(wp + 4);
    __syncthreads();
    *(float4*)&As[ar][ak] = a0;
    *(float4*)&As[ar][ak + 4] = a1;
    *(float4*)&Ws[wr][wc] = w0;
    *(float4*)&Ws[wr][wc + 4] = w1;
    __syncthreads();
#pragma unroll
    for (int kk = 0; kk < 32; kk += 4) {
      f32x4 av[4], wv[4];
#pragma unroll
      for (int i = 0; i < 4; i++) av[i] = *(const f32x4*)&As[ty * 4 + i][kk];
#pragma unroll
      for (int s = 0; s < 4; s++) wv[s] = *(const f32x4*)&Ws[kk + s][tx * 4];
#pragma unroll
      for (int i = 0; i < 4; i++) {
        acc[i] += av[i].x * wv[0];
        acc[i] += av[i].y * wv[1];
        acc[i] += av[i].z * wv[2];
        acc[i] += av[i].w * wv[3];
      }
    }
  }

  int colbase = bj * 64 + tx * 4;
  f32x4 bv = *(const f32x4*)(bias + colbase);
#pragma unroll
  for (int i = 0; i < 4; i++) {
    f32x4 o = acc[i] + bv;
    o.x = fmaxf(o.x, 0.f);
    o.y = fmaxf(o.y, 0.f);
    o.z = fmaxf(o.z, 0.f);
    o.w = fmaxf(o.w, 0.f);
    *(f32x4*)(C + (size_t)(bi * 64 + ty * 4 + i) * 256 + colbase) = o;
  }
}

// ---- final layer: out[r] = dot(h2[r], W3) + b3 ----------------------------
__global__ __launch_bounds__(256) void layer3_kernel(const float* __restrict__ h2,
                                                     const float* __restrict__ W3,
                                                     const float* __restrict__ b3,
                                                     float* __restrict__ out) {
  int tid = threadIdx.x;
  int lane = tid & 63;
  int row = blockIdx.x * 4 + (tid >> 6);
  f32x4 h = *(const f32x4*)(h2 + (size_t)row * 256 + lane * 4);
  f32x4 w = *(const f32x4*)(W3 + lane * 4);
  float s = h.x * w.x + h.y * w.y + h.z * w.z + h.w * w.w;
#pragma unroll
  for (int off = 32; off; off >>= 1) s += __shfl_xor(s, off);
  if (lane == 0) out[row] = s + b3[0];
}

extern "C" void kernel_launch(void* const* d_in, const int* in_sizes, int n_in,
                              void* d_out, int out_size, void* d_ws, size_t ws_size,
                              hipStream_t stream) {
  const float* x  = (const float*)d_in[0];
  const float* q  = (const float*)d_in[1];
  const float* W1 = (const float*)d_in[2];
  const float* b1 = (const float*)d_in[3];
  const float* W2 = (const float*)d_in[4];
  const float* b2 = (const float*)d_in[5];
  const float* W3 = (const float*)d_in[6];
  const float* b3 = (const float*)d_in[7];
  float* out = (float*)d_out;

  char* ws = (char*)d_ws;
  __hip_bfloat16* xn = (__hip_bfloat16*)(ws);        // 2 MB
  int*   cnt   = (int*)(ws + 0x200000);              // 32 KB
  float* W1T   = (float*)(ws + 0x210000);            // 224 KB
  float* W2T   = (float*)(ws + 0x250000);            // 256 KB
  float* feats = (float*)(ws + 0x290000);            // 7 MB
  float* h1    = (float*)(ws + 0x990000);            // 8 MB
  float* h2    = (float*)(ws + 0x1190000);           // 8 MB

  norm_kernel<<<dim3(2048), dim3(256), 0, stream>>>(x, xn, cnt);
  tw_kernel<<<dim3(KPAD + 256), dim3(256), 0, stream>>>(W1, W2, W1T, W2T);
  gram_kernel<<<dim3(2080), dim3(256), 0, stream>>>(xn, cnt);
  feats_kernel<<<dim3(2048), dim3(256), 0, stream>>>(x, q, cnt, feats);
  gemm_relu<KPAD><<<dim3(128, 4), dim3(256), 0, stream>>>(feats, W1T, b1, h1);
  gemm_relu<256><<<dim3(128, 4), dim3(256), 0, stream>>>(h1, W2T, b2, h2);
  layer3_kernel<<<dim3(2048), dim3(256), 0, stream>>>(h2, W3, b3, out);
}

// Round 3
// 111.717 us; speedup vs baseline: 1.5645x; 1.1325x over previous
//
#include <hip/hip_runtime.h>
#include <hip/hip_bf16.h>

typedef __attribute__((ext_vector_type(8))) short bf16x8;
typedef __attribute__((ext_vector_type(4))) float f32x4;
typedef unsigned int uint;

#define NROWS 8192
#define F_DIM 128
#define Q_DIM 64
#define KPAD  224   // 193 padded to 7*32
#define H_DIM 256

// pack fp32 -> (lo_bf16 << 16) | hi_bf16   (v ~= hi + lo, |err| <~ 2^-17 |v|)
static __device__ inline unsigned short bf_bits(__hip_bfloat16 b) {
  unsigned short u; __builtin_memcpy(&u, &b, 2); return u;
}
static __device__ inline uint packhl(float v) {
  __hip_bfloat16 h = __float2bfloat16(v);
  float hf = __bfloat162float(h);
  __hip_bfloat16 l = __float2bfloat16(v - hf);
  return ((uint)bf_bits(l) << 16) | (uint)bf_bits(h);
}

// ---- fused: row norm -> xn(bf16), feats packed hi/lo, zero cnt ------------
__global__ __launch_bounds__(256) void norm_feats_kernel(const float* __restrict__ x,
                                                         const float* __restrict__ q,
                                                         __hip_bfloat16* __restrict__ xn,
                                                         uint* __restrict__ feats_p,
                                                         int* __restrict__ cnt) {
  int tid = threadIdx.x;
  int lane = tid & 63;
  int row = blockIdx.x * 4 + (tid >> 6);
  if (blockIdx.x < 32) cnt[blockIdx.x * 256 + tid] = 0;
  const float2 v = *(const float2*)(x + (size_t)row * F_DIM + lane * 2);
  float s = v.x * v.x + v.y * v.y;
#pragma unroll
  for (int off = 32; off; off >>= 1) s += __shfl_xor(s, off);
  float inv = 1.0f / (sqrtf(s) + 1e-12f);
  __hip_bfloat162 p;
  p.x = __float2bfloat16(v.x * inv);
  p.y = __float2bfloat16(v.y * inv);
  *(__hip_bfloat162*)(xn + (size_t)row * F_DIM + lane * 2) = p;

  uint* frow = feats_p + (size_t)row * KPAD;
  uint2 u;
  u.x = packhl(v.x); u.y = packhl(v.y);
  *(uint2*)(frow + lane * 2) = u;               // cols 0..127 (raw x)
  if (lane < 32) {
    const float2 qv = *(const float2*)(q + (size_t)row * Q_DIM + lane * 2);
    u.x = packhl(qv.x); u.y = packhl(qv.y);
    *(uint2*)(frow + 128 + lane * 2) = u;       // cols 128..191
  } else if (lane < 48) {
    uint2 z = {0u, 0u};
    *(uint2*)(frow + 192 + (lane - 32) * 2) = z; // cols 192..223 (gf + pad)
  }
}

// ---- weights: split+pack W1 [256][193]->[256][224], W2 [256][256] ---------
__global__ __launch_bounds__(256) void prep_w_kernel(const float* __restrict__ W1,
                                                     const float* __restrict__ W2,
                                                     uint* __restrict__ W1P,
                                                     uint* __restrict__ W2P) {
  int b = blockIdx.x, k = threadIdx.x;
  if (b < 256) {
    if (k < KPAD) W1P[b * KPAD + k] = (k < 193) ? packhl(W1[b * 193 + k]) : 0u;
  } else {
    int n = b - 256;
    W2P[n * 256 + k] = packhl(W2[n * 256 + k]);
  }
}

// ---- Gram + threshold + row-count (upper-triangle tiles) ------------------
__global__ __launch_bounds__(256) void gram_kernel(const __hip_bfloat16* __restrict__ xnp,
                                                   int* __restrict__ cnt) {
  __shared__ char smem[65536];
  const short* xn = (const short*)xnp;
  int tid = threadIdx.x;
  int lane = tid & 63;
  int wave = tid >> 6;
  int lr = lane & 15;
  int quad = lane >> 4;

  int t = blockIdx.x;
  int bi = (int)((129.0f - sqrtf(129.0f * 129.0f - 8.0f * (float)t)) * 0.5f);
  while ((bi + 1) * (129 - (bi + 1)) / 2 <= t) bi++;
  while (bi * (129 - bi) / 2 > t) bi--;
  int bj = bi + (t - bi * (129 - bi) / 2);
  int i0 = bi * 128, j0 = bj * 128;

#pragma unroll
  for (int it = 0; it < 16; ++it) {
    int half = it >> 3;
    int row = (it & 7) * 16 + (tid >> 4);
    int chunk = tid & 15;
    int grow = (half ? j0 : i0) + row;
    bf16x8 v = *(const bf16x8*)(xn + (size_t)grow * F_DIM + chunk * 8);
    *(bf16x8*)(smem + half * 32768 + row * 256 + ((chunk ^ (row & 15)) << 4)) = v;
  }
  __syncthreads();

  int wi = (wave >> 1) * 64, wj = (wave & 1) * 64;

  f32x4 acc[4][4];
#pragma unroll
  for (int i = 0; i < 4; i++)
#pragma unroll
    for (int j = 0; j < 4; j++) acc[i][j] = (f32x4){0.f, 0.f, 0.f, 0.f};

#pragma unroll
  for (int kk = 0; kk < 4; kk++) {
    int c = kk * 4 + quad;
    bf16x8 a[4], b[4];
#pragma unroll
    for (int tt = 0; tt < 4; tt++) {
      int row = wi + tt * 16 + lr;
      a[tt] = *(const bf16x8*)(smem + row * 256 + ((c ^ lr) << 4));
    }
#pragma unroll
    for (int tt = 0; tt < 4; tt++) {
      int row = wj + tt * 16 + lr;
      b[tt] = *(const bf16x8*)(smem + 32768 + row * 256 + ((c ^ lr) << 4));
    }
#pragma unroll
    for (int tr = 0; tr < 4; tr++)
#pragma unroll
      for (int tc = 0; tc < 4; tc++)
        acc[tr][tc] = __builtin_amdgcn_mfma_f32_16x16x32_bf16(a[tr], b[tc], acc[tr][tc], 0, 0, 0);
  }

  int i_base = i0 + wi, j_base = j0 + wj;
  bool diag_wave = (i_base == j_base);
  bool offdiag_block = (bi != bj);

  float mx = 0.f;
#pragma unroll
  for (int tr = 0; tr < 4; tr++)
#pragma unroll
    for (int tc = 0; tc < 4; tc++)
#pragma unroll
      for (int r = 0; r < 4; r++) {
        float v = acc[tr][tc][r];
        if (diag_wave && tr == tc && lr == quad * 4 + r) v = 0.f;
        mx = fmaxf(mx, fabsf(v));
      }
  if (__any(mx >= 0.9746f)) {
    for (int tr = 0; tr < 4; tr++)
      for (int tc = 0; tc < 4; tc++)
        for (int r = 0; r < 4; r++) {
          float v = acc[tr][tc][r];
          int row = i_base + tr * 16 + quad * 4 + r;
          int col = j_base + tc * 16 + lr;
          if (v * v >= 0.95f && row != col) {
            atomicAdd(&cnt[row], 1);
            if (offdiag_block) atomicAdd(&cnt[col], 1);
          }
        }
  }
}

// ---- graph feature column + out := b3 -------------------------------------
__global__ __launch_bounds__(256) void gf_kernel(const int* __restrict__ cnt,
                                                 const float* __restrict__ b3,
                                                 uint* __restrict__ feats_p,
                                                 float* __restrict__ out) {
  int i = blockIdx.x * 256 + threadIdx.x;
  feats_p[(size_t)i * KPAD + 192] = packhl((float)cnt[i] * (1.0f / 8192.0f));
  out[i] = b3[0];
}

// ---- hi/lo bf16 MFMA GEMM -------------------------------------------------
// A [8192][K] packed, B [256][K] packed (row n = output unit). Block tile
// 128(m) x 64(n), 4 waves, wave tile 64x32. MODE 1: h = relu(.+bias) -> packed
// store. MODE 2: h2 = relu(.+bias); partial h2 . W3 -> atomicAdd(out).
template <int K, int MODE>
__global__ __launch_bounds__(256) void gemm_mfma(const uint* __restrict__ A,
                                                 const uint* __restrict__ Bp,
                                                 const float* __restrict__ bias,
                                                 uint* __restrict__ Out,
                                                 const float* __restrict__ W3,
                                                 float* __restrict__ out) {
  __shared__ short Ahi[128 * 40];
  __shared__ short Alo[128 * 40];
  __shared__ short Bhi[64 * 40];
  __shared__ short Blo[64 * 40];

  int tid = threadIdx.x;
  int lane = tid & 63;
  int wave = tid >> 6;
  int lr = lane & 15;
  int quad = lane >> 4;
  int mb = blockIdx.x * 128;
  int nb = blockIdx.y * 64;
  int wm = (wave & 1) * 64;
  int wn = (wave >> 1) * 32;

  // staging coords
  int a_row = tid >> 3;          // strided by 32 over iters i: rows tid>>3 + i*32
  int a_c4 = (tid & 7) * 4;      // element offset within 32-chunk
  int b_row = tid >> 3;          // i: +32
  // b covers 64 rows with 2 iters

  f32x4 acc[4][2];
#pragma unroll
  for (int i = 0; i < 4; i++)
#pragma unroll
    for (int j = 0; j < 2; j++) acc[i][j] = (f32x4){0.f, 0.f, 0.f, 0.f};

  constexpr int NIT = K / 32;
  uint4 ar[4], br[2];

  // prefetch iter 0
#pragma unroll
  for (int i = 0; i < 4; i++)
    ar[i] = *(const uint4*)(A + (size_t)(mb + a_row + i * 32) * K + a_c4);
#pragma unroll
  for (int i = 0; i < 2; i++)
    br[i] = *(const uint4*)(Bp + (size_t)(nb + b_row + i * 32) * K + a_c4);

  for (int it = 0; it < NIT; ++it) {
    __syncthreads();
#pragma unroll
    for (int i = 0; i < 4; i++) {
      int r = a_row + i * 32;
      uint h01 = (ar[i].x & 0xffffu) | (ar[i].y << 16);
      uint h23 = (ar[i].z & 0xffffu) | (ar[i].w << 16);
      uint l01 = (ar[i].x >> 16) | (ar[i].y & 0xffff0000u);
      uint l23 = (ar[i].z >> 16) | (ar[i].w & 0xffff0000u);
      *(uint2*)&Ahi[r * 40 + a_c4] = (uint2){h01, h23};
      *(uint2*)&Alo[r * 40 + a_c4] = (uint2){l01, l23};
    }
#pragma unroll
    for (int i = 0; i < 2; i++) {
      int r = b_row + i * 32;
      uint h01 = (br[i].x & 0xffffu) | (br[i].y << 16);
      uint h23 = (br[i].z & 0xffffu) | (br[i].w << 16);
      uint l01 = (br[i].x >> 16) | (br[i].y & 0xffff0000u);
      uint l23 = (br[i].z >> 16) | (br[i].w & 0xffff0000u);
      *(uint2*)&Bhi[r * 40 + a_c4] = (uint2){h01, h23};
      *(uint2*)&Blo[r * 40 + a_c4] = (uint2){l01, l23};
    }
    __syncthreads();

    if (it + 1 < NIT) {
      int k0 = (it + 1) * 32;
#pragma unroll
      for (int i = 0; i < 4; i++)
        ar[i] = *(const uint4*)(A + (size_t)(mb + a_row + i * 32) * K + k0 + a_c4);
#pragma unroll
      for (int i = 0; i < 2; i++)
        br[i] = *(const uint4*)(Bp + (size_t)(nb + b_row + i * 32) * K + k0 + a_c4);
    }

    bf16x8 ahi[4], alo[4], bhi[2], blo[2];
#pragma unroll
    for (int tt = 0; tt < 4; tt++) {
      int r = wm + tt * 16 + lr;
      ahi[tt] = *(const bf16x8*)&Ahi[r * 40 + quad * 8];
      alo[tt] = *(const bf16x8*)&Alo[r * 40 + quad * 8];
    }
#pragma unroll
    for (int tc = 0; tc < 2; tc++) {
      int r = wn + tc * 16 + lr;
      bhi[tc] = *(const bf16x8*)&Bhi[r * 40 + quad * 8];
      blo[tc] = *(const bf16x8*)&Blo[r * 40 + quad * 8];
    }
#pragma unroll
    for (int tt = 0; tt < 4; tt++)
#pragma unroll
      for (int tc = 0; tc < 2; tc++) {
        acc[tt][tc] = __builtin_amdgcn_mfma_f32_16x16x32_bf16(ahi[tt], bhi[tc], acc[tt][tc], 0, 0, 0);
        acc[tt][tc] = __builtin_amdgcn_mfma_f32_16x16x32_bf16(ahi[tt], blo[tc], acc[tt][tc], 0, 0, 0);
        acc[tt][tc] = __builtin_amdgcn_mfma_f32_16x16x32_bf16(alo[tt], bhi[tc], acc[tt][tc], 0, 0, 0);
      }
  }

  if (MODE == 1) {
#pragma unroll
    for (int tc = 0; tc < 2; tc++) {
      int n = nb + wn + tc * 16 + lr;
      float bv = bias[n];
#pragma unroll
      for (int tt = 0; tt < 4; tt++) {
        int m0 = mb + wm + tt * 16 + quad * 4;
#pragma unroll
        for (int r = 0; r < 4; r++) {
          float v = fmaxf(acc[tt][tc][r] + bv, 0.f);
          Out[(size_t)(m0 + r) * 256 + n] = packhl(v);
        }
      }
    }
  } else {
#pragma unroll
    for (int tt = 0; tt < 4; tt++) {
      float s[4] = {0.f, 0.f, 0.f, 0.f};
#pragma unroll
      for (int tc = 0; tc < 2; tc++) {
        int n = nb + wn + tc * 16 + lr;
        float bv = bias[n];
        float w3v = W3[n];
#pragma unroll
        for (int r = 0; r < 4; r++) {
          float v = fmaxf(acc[tt][tc][r] + bv, 0.f);
          s[r] += v * w3v;
        }
      }
#pragma unroll
      for (int r = 0; r < 4; r++) {
        s[r] += __shfl_xor(s[r], 1);
        s[r] += __shfl_xor(s[r], 2);
        s[r] += __shfl_xor(s[r], 4);
        s[r] += __shfl_xor(s[r], 8);
      }
      if (lr == 0) {
        int m0 = mb + wm + tt * 16 + quad * 4;
#pragma unroll
        for (int r = 0; r < 4; r++) atomicAdd(&out[m0 + r], s[r]);
      }
    }
  }
}

extern "C" void kernel_launch(void* const* d_in, const int* in_sizes, int n_in,
                              void* d_out, int out_size, void* d_ws, size_t ws_size,
                              hipStream_t stream) {
  const float* x  = (const float*)d_in[0];
  const float* q  = (const float*)d_in[1];
  const float* W1 = (const float*)d_in[2];
  const float* b1 = (const float*)d_in[3];
  const float* W2 = (const float*)d_in[4];
  const float* b2 = (const float*)d_in[5];
  const float* W3 = (const float*)d_in[6];
  const float* b3 = (const float*)d_in[7];
  float* out = (float*)d_out;

  char* ws = (char*)d_ws;
  __hip_bfloat16* xn = (__hip_bfloat16*)(ws);        // 2 MB
  int*  cnt     = (int*)(ws + 0x200000);             // 32 KB
  uint* W1P     = (uint*)(ws + 0x210000);            // 224 KB
  uint* W2P     = (uint*)(ws + 0x250000);            // 256 KB
  uint* feats_p = (uint*)(ws + 0x290000);            // 8192*224*4 = 7.3 MB
  uint* h1p     = (uint*)(ws + 0x990000);            // 8192*256*4 = 8 MB

  norm_feats_kernel<<<dim3(2048), dim3(256), 0, stream>>>(x, q, xn, feats_p, cnt);
  prep_w_kernel<<<dim3(512), dim3(256), 0, stream>>>(W1, W2, W1P, W2P);
  gram_kernel<<<dim3(2080), dim3(256), 0, stream>>>(xn, cnt);
  gf_kernel<<<dim3(32), dim3(256), 0, stream>>>(cnt, b3, feats_p, out);
  gemm_mfma<KPAD, 1><<<dim3(64, 4), dim3(256), 0, stream>>>(feats_p, W1P, b1, h1p, nullptr, nullptr);
  gemm_mfma<256, 2><<<dim3(64, 4), dim3(256), 0, stream>>>(h1p, W2P, b2, nullptr, W3, out);
}

// Round 5
// 103.767 us; speedup vs baseline: 1.6844x; 1.0766x over previous
//
#include <hip/hip_runtime.h>
#include <hip/hip_bf16.h>

typedef __attribute__((ext_vector_type(8))) short bf16x8;
typedef __attribute__((ext_vector_type(8))) int i32x8;
typedef __attribute__((ext_vector_type(4))) float f32x4;
typedef unsigned int uint;

#define NROWS 8192
#define F_DIM 128
#define Q_DIM 64
#define KPAD  224   // 193 padded to 7*32
#define H_DIM 256

// pack fp32 -> (lo_bf16 << 16) | hi_bf16   (v ~= hi + lo, |err| <~ 2^-17 |v|)
static __device__ inline unsigned short bf_bits(__hip_bfloat16 b) {
  unsigned short u; __builtin_memcpy(&u, &b, 2); return u;
}
static __device__ inline uint packhl(float v) {
  __hip_bfloat16 h = __float2bfloat16(v);
  float hf = __bfloat162float(h);
  __hip_bfloat16 l = __float2bfloat16(v - hf);
  return ((uint)bf_bits(l) << 16) | (uint)bf_bits(h);
}

// ---- fused: row norm -> xn8(fp8 e4m3), feats packed hi/lo, zero cnt,
//      weight split+pack (blocks >= 2048) ----------------------------------
__global__ __launch_bounds__(256) void norm_prep_kernel(const float* __restrict__ x,
                                                        const float* __restrict__ q,
                                                        const float* __restrict__ W1,
                                                        const float* __restrict__ W2,
                                                        unsigned char* __restrict__ xn8,
                                                        uint* __restrict__ feats_p,
                                                        uint* __restrict__ W1P,
                                                        uint* __restrict__ W2P,
                                                        int* __restrict__ cnt) {
  int tid = threadIdx.x;
  if (blockIdx.x >= 2048) {   // weight prep
    int b = blockIdx.x - 2048;
    if (b < 256) {
      if (tid < KPAD) W1P[b * KPAD + tid] = (tid < 193) ? packhl(W1[b * 193 + tid]) : 0u;
    } else {
      int n = b - 256;
      W2P[n * 256 + tid] = packhl(W2[n * 256 + tid]);
    }
    return;
  }
  int lane = tid & 63;
  int row = blockIdx.x * 4 + (tid >> 6);
  if (blockIdx.x < 32) cnt[blockIdx.x * 256 + tid] = 0;
  const float2 v = *(const float2*)(x + (size_t)row * F_DIM + lane * 2);
  float s = v.x * v.x + v.y * v.y;
#pragma unroll
  for (int off = 32; off; off >>= 1) s += __shfl_xor(s, off);
  float inv = 1.0f / (sqrtf(s) + 1e-12f);
  int pk = __builtin_amdgcn_cvt_pk_fp8_f32(v.x * inv, v.y * inv, 0, 0);
  *(unsigned short*)(xn8 + (size_t)row * F_DIM + lane * 2) = (unsigned short)(pk & 0xffff);

  uint* frow = feats_p + (size_t)row * KPAD;
  uint2 u;
  u.x = packhl(v.x); u.y = packhl(v.y);
  *(uint2*)(frow + lane * 2) = u;               // cols 0..127 (raw x)
  if (lane < 32) {
    const float2 qv = *(const float2*)(q + (size_t)row * Q_DIM + lane * 2);
    u.x = packhl(qv.x); u.y = packhl(qv.y);
    *(uint2*)(frow + 128 + lane * 2) = u;       // cols 128..191
  } else if (lane < 48) {
    uint2 z = {0u, 0u};
    *(uint2*)(frow + 192 + (lane - 32) * 2) = z; // cols 192..223 (gf + pad)
  }
}

// ---- Gram via MX-fp8 K=128 MFMA + threshold + row-count -------------------
__global__ __launch_bounds__(256) void gram8_kernel(const unsigned char* __restrict__ xn8,
                                                    int* __restrict__ cnt) {
  __shared__ char smem[32768];  // A 16KB + B 16KB; 128B rows, chunk ^ (row&7) swizzle
  int tid = threadIdx.x;
  int lane = tid & 63;
  int wave = tid >> 6;
  int lr = lane & 15;
  int quad = lane >> 4;

  int t = blockIdx.x;
  int bi = (int)((129.0f - sqrtf(129.0f * 129.0f - 8.0f * (float)t)) * 0.5f);
  while ((bi + 1) * (129 - (bi + 1)) / 2 <= t) bi++;
  while (bi * (129 - bi) / 2 > t) bi--;
  int bj = bi + (t - bi * (129 - bi) / 2);
  int i0 = bi * 128, j0 = bj * 128;

#pragma unroll
  for (int it = 0; it < 8; ++it) {
    int half = it >> 2;                    // 0 = A rows (i0), 1 = B rows (j0)
    int row = (it & 3) * 32 + (tid >> 3);
    int chunk = tid & 7;
    int grow = (half ? j0 : i0) + row;
    uint4 v = *(const uint4*)(xn8 + (size_t)grow * F_DIM + chunk * 16);
    *(uint4*)(smem + half * 16384 + row * 128 + ((chunk ^ (row & 7)) << 4)) = v;
  }
  __syncthreads();

  int wi = (wave >> 1) * 64, wj = (wave & 1) * 64;

  f32x4 acc[4][4];
#pragma unroll
  for (int i = 0; i < 4; i++)
#pragma unroll
    for (int j = 0; j < 4; j++) acc[i][j] = (f32x4){0.f, 0.f, 0.f, 0.f};

  i32x8 a[4], b[4];
#pragma unroll
  for (int tt = 0; tt < 4; tt++) {
    int r = wi + tt * 16 + lr;
    const char* base = smem + r * 128;
    uint4 lo = *(const uint4*)(base + (((2 * quad) ^ (r & 7)) << 4));
    uint4 hi = *(const uint4*)(base + (((2 * quad + 1) ^ (r & 7)) << 4));
    i32x8 f;
    f[0] = lo.x; f[1] = lo.y; f[2] = lo.z; f[3] = lo.w;
    f[4] = hi.x; f[5] = hi.y; f[6] = hi.z; f[7] = hi.w;
    a[tt] = f;
  }
#pragma unroll
  for (int tt = 0; tt < 4; tt++) {
    int r = wj + tt * 16 + lr;
    const char* base = smem + 16384 + r * 128;
    uint4 lo = *(const uint4*)(base + (((2 * quad) ^ (r & 7)) << 4));
    uint4 hi = *(const uint4*)(base + (((2 * quad + 1) ^ (r & 7)) << 4));
    i32x8 f;
    f[0] = lo.x; f[1] = lo.y; f[2] = lo.z; f[3] = lo.w;
    f[4] = hi.x; f[5] = hi.y; f[6] = hi.z; f[7] = hi.w;
    b[tt] = f;
  }

#pragma unroll
  for (int tr = 0; tr < 4; tr++)
#pragma unroll
    for (int tc = 0; tc < 4; tc++)
      acc[tr][tc] = __builtin_amdgcn_mfma_scale_f32_16x16x128_f8f6f4(
          a[tr], b[tc], acc[tr][tc], 0, 0, 0, 0x7f7f7f7f, 0, 0x7f7f7f7f);

  int i_base = i0 + wi, j_base = j0 + wj;
  bool diag_wave = (i_base == j_base);
  bool offdiag_block = (bi != bj);

  float mx = 0.f;
#pragma unroll
  for (int tr = 0; tr < 4; tr++)
#pragma unroll
    for (int tc = 0; tc < 4; tc++)
#pragma unroll
      for (int r = 0; r < 4; r++) {
        float v = acc[tr][tc][r];
        if (diag_wave && tr == tc && lr == quad * 4 + r) v = 0.f;
        mx = fmaxf(mx, fabsf(v));
      }
  if (__any(mx >= 0.9746f)) {
    for (int tr = 0; tr < 4; tr++)
      for (int tc = 0; tc < 4; tc++)
        for (int r = 0; r < 4; r++) {
          float v = acc[tr][tc][r];
          int row = i_base + tr * 16 + quad * 4 + r;
          int col = j_base + tc * 16 + lr;
          if (v * v >= 0.95f && row != col) {
            atomicAdd(&cnt[row], 1);
            if (offdiag_block) atomicAdd(&cnt[col], 1);
          }
        }
  }
}

// ---- hi/lo bf16 MFMA GEMM -------------------------------------------------
// MODE 1 (K=224): A=feats (col 192 injected from cnt), Out = packed relu.
// MODE 2 (K=256): epilogue dot W3 (+b3 once, by==0 && wn==0) -> atomicAdd.
template <int K, int MODE>
__global__ __launch_bounds__(256) void gemm_mfma(const uint* __restrict__ A,
                                                 const uint* __restrict__ Bp,
                                                 const float* __restrict__ bias,
                                                 uint* __restrict__ Out,
                                                 const float* __restrict__ W3,
                                                 const float* __restrict__ b3,
                                                 const int* __restrict__ cnt,
                                                 float* __restrict__ out) {
  __shared__ short Ahi[128 * 40];
  __shared__ short Alo[128 * 40];
  __shared__ short Bhi[64 * 40];
  __shared__ short Blo[64 * 40];

  int tid = threadIdx.x;
  int lane = tid & 63;
  int wave = tid >> 6;
  int lr = lane & 15;
  int quad = lane >> 4;
  int mb = blockIdx.x * 128;
  int nb = blockIdx.y * 64;
  int wm = (wave & 1) * 64;
  int wn = (wave >> 1) * 32;

  int a_row = tid >> 3;
  int a_c4 = (tid & 7) * 4;

  // cnt -> graph-feature column (col 192), loaded up-front (gemm1 only)
  uint gf[4];
  if (MODE == 1 && a_c4 == 0) {
#pragma unroll
    for (int i = 0; i < 4; i++)
      gf[i] = packhl((float)cnt[mb + a_row + i * 32] * (1.0f / 8192.0f));
  }

  f32x4 acc[4][2];
#pragma unroll
  for (int i = 0; i < 4; i++)
#pragma unroll
    for (int j = 0; j < 2; j++) acc[i][j] = (f32x4){0.f, 0.f, 0.f, 0.f};

  constexpr int NIT = K / 32;
  uint4 ar[4], br[2];

#pragma unroll
  for (int i = 0; i < 4; i++)
    ar[i] = *(const uint4*)(A + (size_t)(mb + a_row + i * 32) * K + a_c4);
#pragma unroll
  for (int i = 0; i < 2; i++)
    br[i] = *(const uint4*)(Bp + (size_t)(nb + a_row + i * 32) * K + a_c4);

  for (int it = 0; it < NIT; ++it) {
    if (MODE == 1 && it == 6 && a_c4 == 0) {
#pragma unroll
      for (int i = 0; i < 4; i++) ar[i].x = gf[i];   // col 192
    }
    __syncthreads();
#pragma unroll
    for (int i = 0; i < 4; i++) {
      int r = a_row + i * 32;
      uint h01 = (ar[i].x & 0xffffu) | (ar[i].y << 16);
      uint h23 = (ar[i].z & 0xffffu) | (ar[i].w << 16);
      uint l01 = (ar[i].x >> 16) | (ar[i].y & 0xffff0000u);
      uint l23 = (ar[i].z >> 16) | (ar[i].w & 0xffff0000u);
      *(uint2*)&Ahi[r * 40 + a_c4] = (uint2){h01, h23};
      *(uint2*)&Alo[r * 40 + a_c4] = (uint2){l01, l23};
    }
#pragma unroll
    for (int i = 0; i < 2; i++) {
      int r = a_row + i * 32;
      uint h01 = (br[i].x & 0xffffu) | (br[i].y << 16);
      uint h23 = (br[i].z & 0xffffu) | (br[i].w << 16);
      uint l01 = (br[i].x >> 16) | (br[i].y & 0xffff0000u);
      uint l23 = (br[i].z >> 16) | (br[i].w & 0xffff0000u);
      *(uint2*)&Bhi[r * 40 + a_c4] = (uint2){h01, h23};
      *(uint2*)&Blo[r * 40 + a_c4] = (uint2){l01, l23};
    }
    __syncthreads();

    if (it + 1 < NIT) {
      int k0 = (it + 1) * 32;
#pragma unroll
      for (int i = 0; i < 4; i++)
        ar[i] = *(const uint4*)(A + (size_t)(mb + a_row + i * 32) * K + k0 + a_c4);
#pragma unroll
      for (int i = 0; i < 2; i++)
        br[i] = *(const uint4*)(Bp + (size_t)(nb + a_row + i * 32) * K + k0 + a_c4);
    }

    bf16x8 ahi[4], alo[4], bhi[2], blo[2];
#pragma unroll
    for (int tt = 0; tt < 4; tt++) {
      int r = wm + tt * 16 + lr;
      ahi[tt] = *(const bf16x8*)&Ahi[r * 40 + quad * 8];
      alo[tt] = *(const bf16x8*)&Alo[r * 40 + quad * 8];
    }
#pragma unroll
    for (int tc = 0; tc < 2; tc++) {
      int r = wn + tc * 16 + lr;
      bhi[tc] = *(const bf16x8*)&Bhi[r * 40 + quad * 8];
      blo[tc] = *(const bf16x8*)&Blo[r * 40 + quad * 8];
    }
#pragma unroll
    for (int tt = 0; tt < 4; tt++)
#pragma unroll
      for (int tc = 0; tc < 2; tc++) {
        acc[tt][tc] = __builtin_amdgcn_mfma_f32_16x16x32_bf16(ahi[tt], bhi[tc], acc[tt][tc], 0, 0, 0);
        acc[tt][tc] = __builtin_amdgcn_mfma_f32_16x16x32_bf16(ahi[tt], blo[tc], acc[tt][tc], 0, 0, 0);
        acc[tt][tc] = __builtin_amdgcn_mfma_f32_16x16x32_bf16(alo[tt], bhi[tc], acc[tt][tc], 0, 0, 0);
      }
  }

  if (MODE == 1) {
#pragma unroll
    for (int tc = 0; tc < 2; tc++) {
      int n = nb + wn + tc * 16 + lr;
      float bv = bias[n];
#pragma unroll
      for (int tt = 0; tt < 4; tt++) {
        int m0 = mb + wm + tt * 16 + quad * 4;
#pragma unroll
        for (int r = 0; r < 4; r++) {
          float v = fmaxf(acc[tt][tc][r] + bv, 0.f);
          Out[(size_t)(m0 + r) * 256 + n] = packhl(v);
        }
      }
    }
  } else {
    // b3 added exactly once per row: only the wn==0 wave of the by==0 block
    float b3v = (blockIdx.y == 0 && wn == 0) ? b3[0] : 0.f;
#pragma unroll
    for (int tt = 0; tt < 4; tt++) {
      float s[4] = {0.f, 0.f, 0.f, 0.f};
#pragma unroll
      for (int tc = 0; tc < 2; tc++) {
        int n = nb + wn + tc * 16 + lr;
        float bv = bias[n];
        float w3v = W3[n];
#pragma unroll
        for (int r = 0; r < 4; r++) {
          float v = fmaxf(acc[tt][tc][r] + bv, 0.f);
          s[r] += v * w3v;
        }
      }
#pragma unroll
      for (int r = 0; r < 4; r++) {
        s[r] += __shfl_xor(s[r], 1);
        s[r] += __shfl_xor(s[r], 2);
        s[r] += __shfl_xor(s[r], 4);
        s[r] += __shfl_xor(s[r], 8);
      }
      if (lr == 0) {
        int m0 = mb + wm + tt * 16 + quad * 4;
#pragma unroll
        for (int r = 0; r < 4; r++) atomicAdd(&out[m0 + r], s[r] + b3v);
      }
    }
  }
}

extern "C" void kernel_launch(void* const* d_in, const int* in_sizes, int n_in,
                              void* d_out, int out_size, void* d_ws, size_t ws_size,
                              hipStream_t stream) {
  const float* x  = (const float*)d_in[0];
  const float* q  = (const float*)d_in[1];
  const float* W1 = (const float*)d_in[2];
  const float* b1 = (const float*)d_in[3];
  const float* W2 = (const float*)d_in[4];
  const float* b2 = (const float*)d_in[5];
  const float* W3 = (const float*)d_in[6];
  const float* b3 = (const float*)d_in[7];
  float* out = (float*)d_out;

  char* ws = (char*)d_ws;
  unsigned char* xn8 = (unsigned char*)(ws);         // 1 MB
  int*  cnt     = (int*)(ws + 0x100000);             // 32 KB
  uint* W1P     = (uint*)(ws + 0x110000);            // 224 KB
  uint* W2P     = (uint*)(ws + 0x150000);            // 256 KB
  uint* feats_p = (uint*)(ws + 0x190000);            // 7.3 MB
  uint* h1p     = (uint*)(ws + 0x890000);            // 8 MB

  hipMemsetAsync(d_out, 0, (size_t)out_size * 4, stream);
  norm_prep_kernel<<<dim3(2560), dim3(256), 0, stream>>>(x, q, W1, W2, xn8, feats_p, W1P, W2P, cnt);
  gram8_kernel<<<dim3(2080), dim3(256), 0, stream>>>(xn8, cnt);
  gemm_mfma<KPAD, 1><<<dim3(64, 4), dim3(256), 0, stream>>>(feats_p, W1P, b1, h1p, nullptr, nullptr, cnt, nullptr);
  gemm_mfma<256, 2><<<dim3(64, 4), dim3(256), 0, stream>>>(h1p, W2P, b2, nullptr, W3, b3, nullptr, out);
}